// Round 7
// baseline (606.118 us; speedup 1.0000x reference)
//
#include <hip/hip_runtime.h>
#include <hip/hip_bf16.h>
#include <cstddef>

using u16 = unsigned short;
using short8 = __attribute__((ext_vector_type(8))) short;
using f32x4 = __attribute__((ext_vector_type(4))) float;

constexpr int B_   = 8192;
constexpr int IN_  = 256;
constexpr int COND_= 1024;
constexpr int H_   = 1024;
constexpr int LAT_ = 128;
constexpr int NE_  = 6;
constexpr int GH_  = 64;
constexpr int INP_ = 1152;   // LAT+COND == LAT+H
constexpr int K0_  = 1536;   // IN+COND+IN
constexpr int K1_  = 1280;   // H+IN

constexpr int BK = 64;       // K-step for the small 4-wave kernel

typedef const __attribute__((address_space(1))) void gv_t;
typedef __attribute__((address_space(3))) void lv_t;
#define GLDS(g, l) __builtin_amdgcn_global_load_lds((gv_t*)(g), (lv_t*)(l), 16, 0, 0)

__device__ __forceinline__ u16 f2b(float f) {
  __hip_bfloat16 h = __float2bfloat16(f);
  return *reinterpret_cast<u16*>(&h);
}
__device__ __forceinline__ float elu1(float x) { return x > 0.f ? x : (__expf(x) - 1.f); }

// ---------------- transpose + f32->bf16 convert: in [R][C] f32 -> out [C][R] bf16
__global__ void k_transpose(const float* __restrict__ in, u16* __restrict__ out,
                            int R, int C, long inStride, long outStride) {
  __shared__ float t[32][33];
  const float* ip = in + (long)blockIdx.z * inStride;
  u16* op = out + (long)blockIdx.z * outStride;
  int c0 = blockIdx.x * 32, r0 = blockIdx.y * 32;
  int tx = threadIdx.x, ty = threadIdx.y; // 32x8
#pragma unroll
  for (int i = 0; i < 4; i++) {
    int r = r0 + ty + i * 8, c = c0 + tx;
    if (r < R && c < C) t[ty + i * 8][tx] = ip[(long)r * C + c];
  }
  __syncthreads();
#pragma unroll
  for (int i = 0; i < 4; i++) {
    int c = c0 + ty + i * 8, r = r0 + tx;
    if (r < R && c < C) op[(long)c * R + r] = f2b(t[tx][ty + i * 8]);
  }
}

// ---------------- build A0 = [x|y|x] bf16 and A1 x-columns
__global__ void k_prep(const float* __restrict__ x, const float* __restrict__ y,
                       u16* __restrict__ A0, u16* __restrict__ A1) {
  long idx = (long)blockIdx.x * blockDim.x + threadIdx.x;
  long n0 = (long)B_ * K0_;
  if (idx < n0) {
    int b = (int)(idx / K0_), c = (int)(idx % K0_);
    float v;
    if (c < IN_)            v = x[(long)b * IN_ + c];
    else if (c < IN_+COND_) v = y[(long)b * COND_ + (c - IN_)];
    else                    v = x[(long)b * IN_ + (c - IN_ - COND_)];
    A0[idx] = f2b(v);
  } else {
    long j = idx - n0;
    if (j < (long)B_ * IN_) {
      int b = (int)(j / IN_), c = (int)(j % IN_);
      A1[(long)b * K1_ + H_ + c] = f2b(x[(long)b * IN_ + c]);
    }
  }
}

// ---------------- z = mu + eps*exp(0.5*lv); fill ZY=[z|y], z-cols of D1,D2
__global__ void k_z(const float* __restrict__ mu, const float* __restrict__ lv,
                    const float* __restrict__ eps, const float* __restrict__ y,
                    u16* __restrict__ ZY, u16* __restrict__ D1, u16* __restrict__ D2) {
  long idx = (long)blockIdx.x * blockDim.x + threadIdx.x;
  if (idx >= (long)B_ * INP_) return;
  int b = (int)(idx / INP_), c = (int)(idx % INP_);
  if (c < LAT_) {
    long o = (long)b * LAT_ + c;
    float z = mu[o] + eps[o] * __expf(0.5f * lv[o]);
    u16 zb = f2b(z);
    ZY[idx] = zb; D1[idx] = zb; D2[idx] = zb;
  } else {
    ZY[idx] = f2b(y[(long)b * COND_ + (c - LAT_)]);
  }
}

// ---------------- gating tail: g2 = elu(g1@w1+b1); logits = g2@w2+b2; softmax
__global__ __launch_bounds__(256) void k_gate(const float* __restrict__ G1,
    const float* __restrict__ w1, const float* __restrict__ b1,
    const float* __restrict__ w2, const float* __restrict__ b2,
    float* __restrict__ coeff) {
  __shared__ float W1[64][65];
  __shared__ float W2[64][8];
  __shared__ float B1[64], B2[8];
  int tid = threadIdx.x;
  for (int i = tid; i < 64 * 64; i += 256) W1[i >> 6][i & 63] = w1[i];
  for (int i = tid; i < 64 * 6; i += 256) W2[i / 6][i % 6] = w2[i];
  if (tid < 64) B1[tid] = b1[tid];
  if (tid < 8)  B2[tid] = (tid < 6) ? b2[tid] : 0.f;
  __syncthreads();
  int row = blockIdx.x * 256 + tid;
  const float* gr = G1 + (long)row * GH_;
  float g[64];
#pragma unroll
  for (int i = 0; i < 16; i++) {
    float4 v = *(const float4*)(gr + i * 4);
    g[i*4] = v.x; g[i*4+1] = v.y; g[i*4+2] = v.z; g[i*4+3] = v.w;
  }
  float lg[6];
#pragma unroll
  for (int e = 0; e < 6; e++) lg[e] = B2[e];
  for (int n = 0; n < 64; n++) {
    float s = B1[n];
#pragma unroll
    for (int k = 0; k < 64; k++) s += g[k] * W1[k][n];
    s = elu1(s);
#pragma unroll
    for (int e = 0; e < 6; e++) lg[e] += s * W2[n][e];
  }
  float m = lg[0];
#pragma unroll
  for (int e = 1; e < 6; e++) m = fmaxf(m, lg[e]);
  float p[6], sum = 0.f;
#pragma unroll
  for (int e = 0; e < 6; e++) { p[e] = __expf(lg[e] - m); sum += p[e]; }
  float inv = 1.f / sum;
#pragma unroll
  for (int e = 0; e < 6; e++) coeff[(long)row * 6 + e] = p[e] * inv;
}

// ================= 4-wave co-tenant GEMM (+MoE): BM=BN=128, BK=32, 256 thr.
// 2 blocks/CU (LDS 51 KB). 3-buffer ring, depth-2 prefetch, counted vmcnt(4),
// ONE barrier per step, setprio around MFMA. 64B LDS rows: XOR swizzle
// slot^=(r&3)^((r>>2)&3) via pre-swizzled global source (rule #21); read
// slot = hi ^ (lr&3) ^ ((lr>>2)&3)  -> conflict-free (verified bank map).
// Row-slab XCD swizzle: XCD owns 8 row-blocks (1024 rows, 2.36MB L2-resident).
// Serpentine K across experts. KK = KSTEPS*32 == lda == expert row length.
template<int KSTEPS, int E, bool MOE>
__global__ __launch_bounds__(256, 2) void k_g4(
    const u16* __restrict__ A,
    const u16* __restrict__ WT,
    const float* __restrict__ bias,     // MOE: [E][N]; dense: [N]
    const float* __restrict__ coeff,    // MOE: [M][6]
    int N,
    u16* __restrict__ outH, int ldo)
{
  constexpr int KK = KSTEPS * 32;
  constexpr int T = E * KSTEPS;
  __shared__ __align__(16) u16 As[3][128][32];
  __shared__ __align__(16) u16 Bs[3][128][32];
  __shared__ float Cf[MOE ? 128 : 1][6];

  const int tid = threadIdx.x;
  const int lane = tid & 63, w = tid >> 6;       // 4 waves
  const int wr = w >> 1, wc = w & 1;             // 2 x 2, wave-tile 64x64
  // row-slab XCD swizzle (grid 64 x 8 = 512 blocks)
  const int lin = blockIdx.x + blockIdx.y * gridDim.x;
  const int rb  = (lin & 7) * 8 + ((lin >> 3) & 7);
  const int cp  = lin >> 6;
  const int brow = rb * 128, bcol = cp * 128;
  const int lr = lane & 15, hi = lane >> 4;
  const int xsw3 = (lr & 3) ^ ((lr >> 2) & 3);   // read-side slot XOR

  if (MOE) {
    if (tid < 128) {
#pragma unroll
      for (int e2 = 0; e2 < 6; e2++)
        Cf[tid][e2] = coeff[(long)(brow + tid) * 6 + e2];
    }
    __syncthreads();   // Cf visible + its loads drained before vmcnt counting
  }

  f32x4 acc[4][4];
#pragma unroll
  for (int m = 0; m < 4; m++)
#pragma unroll
    for (int n = 0; n < 4; n++)
#pragma unroll
      for (int r = 0; r < 4; r++) acc[m][n][r] = 0.f;
  f32x4 pacc[MOE ? 4 : 1][MOE ? 4 : 1];
  if constexpr (MOE) {
#pragma unroll
    for (int m = 0; m < 4; m++)
#pragma unroll
      for (int n = 0; n < 4; n++)
#pragma unroll
        for (int r = 0; r < 4; r++) pacc[m][n][r] = 0.f;
  }

  // staging: 64B rows; lane l -> row +(l>>2), dest slot l&3 (linear lane*16);
  // global source slot = (l&3) ^ (row&3) ^ ((row>>2)&3) -> swizzled store.
  const int srow = w * 16 + (lane >> 2);         // 4 waves cover rows 0..63
  const int sdst = (lane & 3) * 8;
  const int ssrc = (((lane & 3) ^ ((lane >> 2) & 3) ^ ((lane >> 4) & 3))) * 8;
  const u16* Asrc = A + (long)(brow + srow) * KK + ssrc;
  const u16* Bsrc = WT + (long)(bcol + srow) * KK + ssrc;

  auto STAGE = [&](int t2, int buf) {            // 4 GLDS per wave
    const int e2 = (E == 1) ? 0 : (t2 / KSTEPS);
    int k2 = (E == 1) ? t2 : (t2 % KSTEPS);
    if (E > 1 && (e2 & 1)) k2 = KSTEPS - 1 - k2; // serpentine K
    const u16* ap = Asrc + (long)k2 * 32;
    const u16* bp = Bsrc + (long)e2 * ((long)N * KK) + (long)k2 * 32;
    GLDS(ap,                  &As[buf][srow][sdst]);
    GLDS(ap + (long)64 * KK,  &As[buf][64 + srow][sdst]);
    GLDS(bp,                  &Bs[buf][srow][sdst]);
    GLDS(bp + (long)64 * KK,  &Bs[buf][64 + srow][sdst]);
  };

  STAGE(0, 0);
  STAGE(1, 1);
  asm volatile("s_waitcnt vmcnt(4)" ::: "memory");   // tile0 landed (tile1 in flight)
  asm volatile("s_barrier" ::: "memory");

  for (int t = 0; t < T; ++t) {
    const int cur = t % 3;
    // ds_read this step's fragments (compiler inserts lgkm waits before MFMA)
    short8 af[4], bfr[4];
    const int cc = (hi ^ xsw3) << 3;
#pragma unroll
    for (int m = 0; m < 4; m++)
      af[m] = *(const short8*)&As[cur][wr * 64 + m * 16 + lr][cc];
#pragma unroll
    for (int n = 0; n < 4; n++)
      bfr[n] = *(const short8*)&Bs[cur][wc * 64 + n * 16 + lr][cc];
    // prefetch tile t+2 (its 4 loads stay in flight across the barrier)
    if (t + 2 < T) STAGE(t + 2, (t + 2) % 3);
    __builtin_amdgcn_s_setprio(1);
#pragma unroll
    for (int m = 0; m < 4; m++)
#pragma unroll
      for (int n = 0; n < 4; n++) {
        if constexpr (MOE)
          pacc[m][n] = __builtin_amdgcn_mfma_f32_16x16x32_bf16(af[m], bfr[n], pacc[m][n], 0, 0, 0);
        else
          acc[m][n] = __builtin_amdgcn_mfma_f32_16x16x32_bf16(af[m], bfr[n], acc[m][n], 0, 0, 0);
      }
    __builtin_amdgcn_s_setprio(0);
    // end-of-step: tile t+1's 4 loads landed; tile t+2's 4 stay in flight
    if (t + 1 < T) {
      if (t + 2 < T) asm volatile("s_waitcnt vmcnt(4)" ::: "memory");
      else           asm volatile("s_waitcnt vmcnt(0)" ::: "memory");
    }
    asm volatile("s_barrier" ::: "memory");

    if constexpr (MOE) {
      if ((t + 1) % KSTEPS == 0) {               // end of expert: merge
        const int e = t / KSTEPS;
#pragma unroll
        for (int m = 0; m < 4; m++)
#pragma unroll
          for (int r = 0; r < 4; r++) {
            float c = Cf[wr * 64 + m * 16 + hi * 4 + r][e];
#pragma unroll
            for (int n = 0; n < 4; n++) acc[m][n][r] += c * pacc[m][n][r];
          }
        if (t + 1 < T) {
#pragma unroll
          for (int m = 0; m < 4; m++)
#pragma unroll
            for (int n = 0; n < 4; n++)
#pragma unroll
              for (int r = 0; r < 4; r++) pacc[m][n][r] = 0.f;
        }
      }
    }
  }

  // epilogue
#pragma unroll
  for (int m = 0; m < 4; m++)
#pragma unroll
    for (int n = 0; n < 4; n++) {
      const int col = bcol + wc * 64 + n * 16 + lr;
#pragma unroll
      for (int r = 0; r < 4; r++) {
        const int rowl = wr * 64 + m * 16 + hi * 4 + r;
        const long row = brow + rowl;
        float v = acc[m][n][r];
        if constexpr (MOE) {
          float bv = 0.f;
#pragma unroll
          for (int e = 0; e < 6; e++) bv += Cf[rowl][e] * bias[(long)e * N + col];
          v += bv;
        } else {
          v += bias[col];
        }
        v = elu1(v);
        outH[row * (long)ldo + col] = f2b(v);
      }
    }
}

// ---------------- 4-wave GEMM (+MoE) for small-N layers (R3 structure, BK=64)
template<int MREP, bool MOE>
__global__ __launch_bounds__(256, 2) void k_gemm(
    const u16* __restrict__ A, int lda,
    const u16* __restrict__ WT, long wstride,
    const float* __restrict__ bias,
    const float* __restrict__ coeff,
    int N, int K, int E,
    u16* __restrict__ outH, float* __restrict__ outF, float* __restrict__ outF2,
    int ldo, int splitcol, const float* __restrict__ bias2, int act)
{
  constexpr int BMt = 32 * MREP;
  __shared__ __align__(16) u16 As[2][BMt][BK];
  __shared__ __align__(16) u16 Bs[2][128][BK];
  __shared__ float Cf[MOE ? BMt : 1][8];

  const int tid = threadIdx.x;
  const int lane = tid & 63, w = tid >> 6;
  const int wr = w >> 1, wc = w & 1;
  const int brow = blockIdx.x * BMt, bcol = blockIdx.y * 128;
  const int lr = lane & 15, hi = lane >> 4;
  const int lk = hi * 8;
  const int xsw = (lr & 7) << 3;

  if (MOE && tid < BMt) {
#pragma unroll
    for (int e2 = 0; e2 < 8; e2++)
      Cf[tid][e2] = (e2 < 6) ? coeff[(long)(brow + tid) * 6 + e2] : 0.f;
  }

  f32x4 acc[MREP][4];
#pragma unroll
  for (int m = 0; m < MREP; m++)
#pragma unroll
    for (int n = 0; n < 4; n++)
#pragma unroll
      for (int r = 0; r < 4; r++) acc[m][n][r] = 0.f;

  const int srow = w * 8 + (lane >> 3);
  const int sdst = (lane & 7) * 8;
  const int ssrc = ((lane & 7) ^ ((lane >> 3) & 7)) * 8;
  const u16* Asrc = A + (long)(brow + srow) * lda + ssrc;
  const u16* Bsrc = WT + (long)(bcol + srow) * K + ssrc;
  const int KSTEPS = K / BK;

  int cur = 0;
#pragma unroll
  for (int i = 0; i < BMt / 32; i++)
    GLDS(Asrc + (long)(i * 32) * lda, &As[0][i * 32 + srow][sdst]);
#pragma unroll
  for (int i = 0; i < 4; i++)
    GLDS(Bsrc + (long)(i * 32) * K, &Bs[0][i * 32 + srow][sdst]);

  for (int e = 0; e < E; ++e) {
    f32x4 pacc[MREP][4];
    if constexpr (MOE) {
#pragma unroll
      for (int m = 0; m < MREP; m++)
#pragma unroll
        for (int n = 0; n < 4; n++)
#pragma unroll
          for (int r = 0; r < 4; r++) pacc[m][n][r] = 0.f;
    }

    for (int kt = 0; kt < KSTEPS; ++kt) {
      __syncthreads();
      int ne = e, nk = kt + 1;
      if (nk == KSTEPS) { nk = 0; ne = e + 1; }
      if (ne < E) {
        const u16* ap = Asrc + (long)nk * BK;
        const u16* bp = Bsrc + (long)ne * wstride + (long)nk * BK;
#pragma unroll
        for (int i = 0; i < BMt / 32; i++)
          GLDS(ap + (long)(i * 32) * lda, &As[cur ^ 1][i * 32 + srow][sdst]);
#pragma unroll
        for (int i = 0; i < 4; i++)
          GLDS(bp + (long)(i * 32) * K, &Bs[cur ^ 1][i * 32 + srow][sdst]);
      }
#pragma unroll
      for (int kk = 0; kk < BK; kk += 32) {
        short8 af[MREP], bfr[4];
        const int cc = (kk + lk) ^ xsw;
#pragma unroll
        for (int m = 0; m < MREP; m++)
          af[m] = *(const short8*)&As[cur][wr * (16 * MREP) + m * 16 + lr][cc];
#pragma unroll
        for (int n = 0; n < 4; n++)
          bfr[n] = *(const short8*)&Bs[cur][wc * 64 + n * 16 + lr][cc];
#pragma unroll
        for (int m = 0; m < MREP; m++)
#pragma unroll
          for (int n = 0; n < 4; n++) {
            if constexpr (MOE)
              pacc[m][n] = __builtin_amdgcn_mfma_f32_16x16x32_bf16(af[m], bfr[n], pacc[m][n], 0, 0, 0);
            else
              acc[m][n] = __builtin_amdgcn_mfma_f32_16x16x32_bf16(af[m], bfr[n], acc[m][n], 0, 0, 0);
          }
      }
      cur ^= 1;
    }
    if constexpr (MOE) {
#pragma unroll
      for (int m = 0; m < MREP; m++)
#pragma unroll
        for (int r = 0; r < 4; r++) {
          float c = Cf[wr * (16 * MREP) + m * 16 + hi * 4 + r][e];
#pragma unroll
          for (int n = 0; n < 4; n++) acc[m][n][r] += c * pacc[m][n][r];
        }
    }
  }

#pragma unroll
  for (int m = 0; m < MREP; m++)
#pragma unroll
    for (int n = 0; n < 4; n++) {
      int col = bcol + wc * 64 + n * 16 + lr;
      if (col >= N) continue;
#pragma unroll
      for (int r = 0; r < 4; r++) {
        int rowl = wr * (16 * MREP) + m * 16 + hi * 4 + r;
        long row = brow + rowl;
        float v = acc[m][n][r];
        if constexpr (MOE) {
          float bv = 0.f;
#pragma unroll
          for (int e = 0; e < 6; e++) bv += Cf[rowl][e] * bias[(long)e * N + col];
          v += bv;
        } else {
          v += (col < splitcol) ? bias[col] : bias2[col - splitcol];
        }
        if (act) v = elu1(v);
        if (outH) outH[row * ldo + col] = f2b(v);
        else if (col < splitcol) outF[row * ldo + col] = v;
        else outF2[row * ldo + (col - splitcol)] = v;
      }
    }
}

extern "C" void kernel_launch(void* const* d_in, const int* in_sizes, int n_in,
                              void* d_out, int out_size, void* d_ws, size_t ws_size,
                              hipStream_t stream) {
  (void)in_sizes; (void)out_size;
  if (n_in < 23) return;
  const float* x      = (const float*)d_in[0];
  const float* y      = (const float*)d_in[1];
  const float* eps    = (const float*)d_in[2];
  const float* enc_w0 = (const float*)d_in[3];
  const float* enc_b0 = (const float*)d_in[4];
  const float* enc_w1 = (const float*)d_in[5];
  const float* enc_b1 = (const float*)d_in[6];
  const float* mu_w   = (const float*)d_in[7];
  const float* mu_b   = (const float*)d_in[8];
  const float* lv_w   = (const float*)d_in[9];
  const float* lv_b   = (const float*)d_in[10];
  const float* g_w0   = (const float*)d_in[11];
  const float* g_b0   = (const float*)d_in[12];
  const float* g_w1   = (const float*)d_in[13];
  const float* g_b1   = (const float*)d_in[14];
  const float* g_w2   = (const float*)d_in[15];
  const float* g_b2   = (const float*)d_in[16];
  const float* exp_w0 = (const float*)d_in[17];
  const float* exp_b0 = (const float*)d_in[18];
  const float* exp_w1 = (const float*)d_in[19];
  const float* exp_b1 = (const float*)d_in[20];
  const float* exp_w2 = (const float*)d_in[21];
  const float* exp_b2 = (const float*)d_in[22];

  char* ws = (char*)d_ws;
  size_t off = 0;
  auto alloc = [&](size_t bytes) -> void* {
    void* p = ws + off; off += (bytes + 255) & ~(size_t)255; return p;
  };
  u16* A0     = (u16*)alloc((size_t)B_ * K0_ * 2);        // enc0 input [x|y|x]; later D1
  u16* A1     = (u16*)alloc((size_t)B_ * K1_ * 2);        // enc1 input [h1|x]; later D2
  u16* H2     = (u16*)alloc((size_t)B_ * H_ * 2);         // enc2 output; later G1/COEFF/ew2T
  u16* ZY     = (u16*)alloc((size_t)B_ * INP_ * 2);       // [z|y]; later ew1T
  u16* encw0T = (u16*)alloc((size_t)K0_ * H_ * 2);
  u16* encw1T = (u16*)alloc((size_t)K1_ * H_ * 2);
  u16* mulvT  = (u16*)alloc((size_t)256 * H_ * 2);
  u16* gw0T   = (u16*)alloc((size_t)GH_ * INP_ * 2);      // OOB-read safe: ew0T follows
  u16* ew0T   = (u16*)alloc((size_t)NE_ * H_ * INP_ * 2);
  if (ws_size < off) return;

  // aliases (lifetime-checked):
  u16* D1 = A0;                                  // A0 dead after enc0
  u16* D2 = A1;                                  // A1 dead after enc1
  float* G1    = (float*)H2;                     // H2 dead after mu/lv
  float* COEFF = (float*)((char*)H2 + (size_t)B_ * GH_ * 4);
  u16* ew2T = (u16*)((char*)H2 + (size_t)4 * 1024 * 1024);   // transposed after mu/lv
  u16* ew1T = ZY;                                            // transposed after moe0

  float* outO = (float*)d_out;                       // [B,256]
  float* muO  = outO + (size_t)B_ * IN_;             // [B,128]
  float* lvO  = muO + (size_t)B_ * LAT_;             // [B,128]

  dim3 tb(32, 8);
  // weight transposes needed before the encoder/gating/moe0
  k_transpose<<<dim3(32, 48), tb, 0, stream>>>(enc_w0, encw0T, K0_, H_, 0, 0);
  k_transpose<<<dim3(32, 40), tb, 0, stream>>>(enc_w1, encw1T, K1_, H_, 0, 0);
  k_transpose<<<dim3(4, 32),  tb, 0, stream>>>(mu_w, mulvT, H_, LAT_, 0, 0);
  k_transpose<<<dim3(4, 32),  tb, 0, stream>>>(lv_w, mulvT + (size_t)LAT_ * H_, H_, LAT_, 0, 0);
  k_transpose<<<dim3(2, 36),  tb, 0, stream>>>(g_w0, gw0T, INP_, GH_, 0, 0);
  k_transpose<<<dim3(32, 36, NE_), tb, 0, stream>>>(exp_w0, ew0T, INP_, H_,
                                                    (long)INP_ * H_, (long)INP_ * H_);
  // concat buffers
  long npr = (long)B_ * K0_ + (long)B_ * IN_;
  k_prep<<<(int)((npr + 255) / 256), 256, 0, stream>>>(x, y, A0, A1);

  // encoder (4-wave co-tenant, 128x128 tiles, grid 64x8 = 512 blocks)
  k_g4<K0_ / 32, 1, false><<<dim3(64, 8), 256, 0, stream>>>(A0, encw0T, enc_b0,
      nullptr, H_, A1, K1_);
  k_g4<K1_ / 32, 1, false><<<dim3(64, 8), 256, 0, stream>>>(A1, encw1T, enc_b1,
      nullptr, H_, H2, H_);
  // mu / logvar (MREP=2: 64x128 tiles -> 256 blocks; f32 split into d_out)
  k_gemm<2, false><<<dim3(B_ / 64, 2), 256, 0, stream>>>(H2, H_, mulvT, 0, mu_b, nullptr,
      256, H_, 1, nullptr, muO, lvO, LAT_, LAT_, lv_b, 0);

  // exp_w2 transpose into freed H2 space (after mu/lv read H2)
  k_transpose<<<dim3(8, 36, NE_), tb, 0, stream>>>(exp_w2, ew2T, INP_, IN_,
                                                   (long)INP_ * IN_, (long)INP_ * IN_);
  // z + [z|y] assembly
  long nz = (long)B_ * INP_;
  k_z<<<(int)((nz + 255) / 256), 256, 0, stream>>>(muO, lvO, eps, y, ZY, D1, D2);

  // gating (MREP=2; N=64 < BN: B-tile OOB rows read into ew0T region, unused cols skipped)
  k_gemm<2, false><<<dim3(B_ / 64, 1), 256, 0, stream>>>(ZY, INP_, gw0T, 0, g_b0, nullptr,
      GH_, INP_, 1, nullptr, G1, nullptr, GH_, GH_, nullptr, 1);
  k_gate<<<B_ / 256, 256, 0, stream>>>(G1, g_w1, g_b1, g_w2, g_b2, COEFF);

  // decoder MoE layer 0: ZY -> D1[:,128:1152]  (4-wave co-tenant MoE)
  k_g4<INP_ / 32, NE_, true><<<dim3(64, 8), 256, 0, stream>>>(ZY, ew0T, exp_b0,
      COEFF, H_, D1 + LAT_, INP_);
  // exp_w1 transpose into freed ZY space (after moe0 read ZY)
  k_transpose<<<dim3(32, 36, NE_), tb, 0, stream>>>(exp_w1, ew1T, INP_, H_,
                                                    (long)INP_ * H_, (long)INP_ * H_);
  // decoder MoE layer 1: D1 -> D2[:,128:1152]
  k_g4<INP_ / 32, NE_, true><<<dim3(64, 8), 256, 0, stream>>>(D1, ew1T, exp_b1,
      COEFF, H_, D2 + LAT_, INP_);
  // decoder MoE layer 2: D2 -> d_out [B,256] f32 (MREP=2 -> 256 blocks)
  k_gemm<2, true><<<dim3(B_ / 64, 2), 256, 0, stream>>>(D2, INP_, ew2T, (long)IN_ * INP_,
      exp_b2, COEFF, IN_, INP_, NE_, nullptr, outO, nullptr, IN_, IN_, nullptr, 0);
}

// Round 8
// 533.470 us; speedup vs baseline: 1.1362x; 1.1362x over previous
//
#include <hip/hip_runtime.h>
#include <hip/hip_bf16.h>
#include <cstddef>

using u16 = unsigned short;
using short8 = __attribute__((ext_vector_type(8))) short;
using f32x4 = __attribute__((ext_vector_type(4))) float;

constexpr int B_   = 8192;
constexpr int IN_  = 256;
constexpr int COND_= 1024;
constexpr int H_   = 1024;
constexpr int LAT_ = 128;
constexpr int NE_  = 6;
constexpr int GH_  = 64;
constexpr int INP_ = 1152;   // LAT+COND == LAT+H
constexpr int K0_  = 1536;   // IN+COND+IN
constexpr int K1_  = 1280;   // H+IN

constexpr int BK = 64;       // K-step (128 B per LDS row)

typedef const __attribute__((address_space(1))) void gv_t;
typedef __attribute__((address_space(3))) void lv_t;
#define GLDS(g, l) __builtin_amdgcn_global_load_lds((gv_t*)(g), (lv_t*)(l), 16, 0, 0)

__device__ __forceinline__ u16 f2b(float f) {
  __hip_bfloat16 h = __float2bfloat16(f);
  return *reinterpret_cast<u16*>(&h);
}
__device__ __forceinline__ float elu1(float x) { return x > 0.f ? x : (__expf(x) - 1.f); }

// ---------------- transpose + f32->bf16 convert (used for ew1T only)
__global__ void k_transpose(const float* __restrict__ in, u16* __restrict__ out,
                            int R, int C, long inStride, long outStride) {
  __shared__ float t[32][33];
  const float* ip = in + (long)blockIdx.z * inStride;
  u16* op = out + (long)blockIdx.z * outStride;
  int c0 = blockIdx.x * 32, r0 = blockIdx.y * 32;
  int tx = threadIdx.x, ty = threadIdx.y; // 32x8
#pragma unroll
  for (int i = 0; i < 4; i++) {
    int r = r0 + ty + i * 8, c = c0 + tx;
    if (r < R && c < C) t[ty + i * 8][tx] = ip[(long)r * C + c];
  }
  __syncthreads();
#pragma unroll
  for (int i = 0; i < 4; i++) {
    int c = c0 + ty + i * 8, r = r0 + tx;
    if (r < R && c < C) op[(long)c * R + r] = f2b(t[tx][ty + i * 8]);
  }
}

// ---------------- k_pre: ALL upfront weight transposes + A0/A1 concat prep.
// Block-id job table (flat 256-thread blocks; transposes use 32x8 mapping):
//   [0,1536)        enc_w0 -> encw0T   (32x48)
//   [1536,2816)     enc_w1 -> encw1T   (32x40)
//   [2816,2944)     mu_w   -> mulvT    (4x32)
//   [2944,3072)     lv_w   -> mulvT+   (4x32)
//   [3072,3144)     g_w0   -> gw0T     (2x36)
//   [3144,10056)    exp_w0 -> ew0T     (32x36 x6)
//   [10056,67400)   prep A0=[x|y|x], A1 x-cols (1 elem/thread)
__global__ __launch_bounds__(256) void k_pre(
    const float* __restrict__ enc_w0, const float* __restrict__ enc_w1,
    const float* __restrict__ mu_w, const float* __restrict__ lv_w,
    const float* __restrict__ g_w0, const float* __restrict__ exp_w0,
    const float* __restrict__ x, const float* __restrict__ y,
    u16* __restrict__ encw0T, u16* __restrict__ encw1T, u16* __restrict__ mulvT,
    u16* __restrict__ gw0T, u16* __restrict__ ew0T,
    u16* __restrict__ A0, u16* __restrict__ A1)
{
  __shared__ float t[32][33];
  const int b = blockIdx.x;
  const int tid = threadIdx.x;
  const int tx = tid & 31, ty = tid >> 5;

  auto tr = [&](const float* in, u16* out, int R, int C, int bx, int by) {
    int c0 = bx * 32, r0 = by * 32;
#pragma unroll
    for (int i = 0; i < 4; i++) {
      int r = r0 + ty + i * 8, c = c0 + tx;
      if (r < R && c < C) t[ty + i * 8][tx] = in[(long)r * C + c];
    }
    __syncthreads();
#pragma unroll
    for (int i = 0; i < 4; i++) {
      int c = c0 + ty + i * 8, r = r0 + tx;
      if (r < R && c < C) out[(long)c * R + r] = f2b(t[tx][ty + i * 8]);
    }
  };

  if (b < 1536)       { tr(enc_w0, encw0T, K0_, H_, b & 31, b >> 5); }
  else if (b < 2816)  { int l = b - 1536; tr(enc_w1, encw1T, K1_, H_, l & 31, l >> 5); }
  else if (b < 2944)  { int l = b - 2816; tr(mu_w, mulvT, H_, LAT_, l & 3, l >> 2); }
  else if (b < 3072)  { int l = b - 2944; tr(lv_w, mulvT + (size_t)LAT_ * H_, H_, LAT_, l & 3, l >> 2); }
  else if (b < 3144)  { int l = b - 3072; tr(g_w0, gw0T, INP_, GH_, l & 1, l >> 1); }
  else if (b < 10056) {
    int l = b - 3144, e = l / 1152, r2 = l % 1152;
    tr(exp_w0 + (long)e * INP_ * H_, ew0T + (long)e * INP_ * H_, INP_, H_, r2 & 31, r2 >> 5);
  } else {
    long idx = (long)(b - 10056) * 256 + tid;
    long n0 = (long)B_ * K0_;
    if (idx < n0) {
      int bb = (int)(idx / K0_), c = (int)(idx % K0_);
      float v;
      if (c < IN_)              v = x[(long)bb * IN_ + c];
      else if (c < IN_ + COND_) v = y[(long)bb * COND_ + (c - IN_)];
      else                      v = x[(long)bb * IN_ + (c - IN_ - COND_)];
      A0[idx] = f2b(v);
    } else {
      long j = idx - n0;
      if (j < (long)B_ * IN_) {
        int bb = (int)(j / IN_), c = (int)(j % IN_);
        A1[(long)bb * K1_ + H_ + c] = f2b(x[(long)bb * IN_ + c]);
      }
    }
  }
}

// ---------------- k_mid: exp_w2 transpose (blocks [0,1728)) + z/ZY/D1/D2 fill
__global__ __launch_bounds__(256) void k_mid(
    const float* __restrict__ exp_w2, u16* __restrict__ ew2T,
    const float* __restrict__ mu, const float* __restrict__ lv,
    const float* __restrict__ eps, const float* __restrict__ y,
    u16* __restrict__ ZY, u16* __restrict__ D1, u16* __restrict__ D2)
{
  __shared__ float t[32][33];
  const int b = blockIdx.x;
  const int tid = threadIdx.x;
  if (b < 1728) {
    const int tx = tid & 31, ty = tid >> 5;
    int e = b / 288, r2 = b % 288;
    const float* in = exp_w2 + (long)e * INP_ * IN_;
    u16* out = ew2T + (long)e * INP_ * IN_;
    int c0 = (r2 & 7) * 32, r0 = (r2 >> 3) * 32;
#pragma unroll
    for (int i = 0; i < 4; i++) {
      int r = r0 + ty + i * 8, c = c0 + tx;
      if (r < INP_ && c < IN_) t[ty + i * 8][tx] = in[(long)r * IN_ + c];
    }
    __syncthreads();
#pragma unroll
    for (int i = 0; i < 4; i++) {
      int c = c0 + ty + i * 8, r = r0 + tx;
      if (r < INP_ && c < IN_) out[(long)c * INP_ + r] = f2b(t[tx][ty + i * 8]);
    }
  } else {
    long idx = (long)(b - 1728) * 256 + tid;
    if (idx >= (long)B_ * INP_) return;
    int bb = (int)(idx / INP_), c = (int)(idx % INP_);
    if (c < LAT_) {
      long o = (long)bb * LAT_ + c;
      float z = mu[o] + eps[o] * __expf(0.5f * lv[o]);
      u16 zb = f2b(z);
      ZY[idx] = zb; D1[idx] = zb; D2[idx] = zb;
    } else {
      ZY[idx] = f2b(y[(long)bb * COND_ + (c - LAT_)]);
    }
  }
}

// ---------------- gating tail: g2 = elu(g1@w1+b1); logits = g2@w2+b2; softmax
__global__ __launch_bounds__(256) void k_gate(const float* __restrict__ G1,
    const float* __restrict__ w1, const float* __restrict__ b1,
    const float* __restrict__ w2, const float* __restrict__ b2,
    float* __restrict__ coeff) {
  __shared__ float W1[64][65];
  __shared__ float W2[64][8];
  __shared__ float B1[64], B2[8];
  int tid = threadIdx.x;
  for (int i = tid; i < 64 * 64; i += 256) W1[i >> 6][i & 63] = w1[i];
  for (int i = tid; i < 64 * 6; i += 256) W2[i / 6][i % 6] = w2[i];
  if (tid < 64) B1[tid] = b1[tid];
  if (tid < 8)  B2[tid] = (tid < 6) ? b2[tid] : 0.f;
  __syncthreads();
  int row = blockIdx.x * 256 + tid;
  const float* gr = G1 + (long)row * GH_;
  float g[64];
#pragma unroll
  for (int i = 0; i < 16; i++) {
    float4 v = *(const float4*)(gr + i * 4);
    g[i*4] = v.x; g[i*4+1] = v.y; g[i*4+2] = v.z; g[i*4+3] = v.w;
  }
  float lg[6];
#pragma unroll
  for (int e = 0; e < 6; e++) lg[e] = B2[e];
  for (int n = 0; n < 64; n++) {
    float s = B1[n];
#pragma unroll
    for (int k = 0; k < 64; k++) s += g[k] * W1[k][n];
    s = elu1(s);
#pragma unroll
    for (int e = 0; e < 6; e++) lg[e] += s * W2[n][e];
  }
  float m = lg[0];
#pragma unroll
  for (int e = 1; e < 6; e++) m = fmaxf(m, lg[e]);
  float p[6], sum = 0.f;
#pragma unroll
  for (int e = 0; e < 6; e++) { p[e] = __expf(lg[e] - m); sum += p[e]; }
  float inv = 1.f / sum;
#pragma unroll
  for (int e = 0; e < 6; e++) coeff[(long)row * 6 + e] = p[e] * inv;
}

// ================= 8-wave big-GEMM (+MoE): BM=256, BN=128, 512 threads.
// R6-proven fine-phase schedule: per K-step 2 phases of
// {8x ds_read | 3 GLDS of tile t+2's half | s_barrier | setprio MFMA | s_barrier};
// vmcnt(6) once per step. 3-buffer ring, row-slab XCD swizzle, serpentine K.
template<int KSTEPS, int E, bool MOE>
__global__ __launch_bounds__(512, 2) void k_gemm8(
    const u16* __restrict__ A,
    const u16* __restrict__ WT,
    const float* __restrict__ bias,     // MOE: [E][N]; dense: [N]
    const float* __restrict__ coeff,    // MOE: [M][6]
    int N,
    u16* __restrict__ outH, int ldo)
{
  constexpr int KK = KSTEPS * BK;
  constexpr int T = E * KSTEPS;
  __shared__ __align__(16) u16 As[3][256][BK];
  __shared__ __align__(16) u16 Bs[3][128][BK];
  __shared__ float Cf[MOE ? 256 : 1][8];

  const int tid = threadIdx.x;
  const int lane = tid & 63, w = tid >> 6;       // 8 waves
  const int wr = w >> 1, wc = w & 1;             // 4 x 2
  const int lin = blockIdx.x + blockIdx.y * gridDim.x;
  const int rb  = (lin & 7) * 4 + ((lin >> 3) & 3);  // XCD owns 4 row-blocks
  const int cp  = lin >> 5;
  const int brow = rb * 256, bcol = cp * 128;
  const int lr = lane & 15, hi = lane >> 4;
  const int lk = hi * 8;
  const int xsw = (lr & 7) << 3;

  if (MOE) {
    if (tid < 256) {
#pragma unroll
      for (int e2 = 0; e2 < 8; e2++)
        Cf[tid][e2] = (e2 < 6) ? coeff[(long)(brow + tid) * 6 + e2] : 0.f;
    }
    __syncthreads();
  }

  f32x4 acc[4][4];
#pragma unroll
  for (int m = 0; m < 4; m++)
#pragma unroll
    for (int n = 0; n < 4; n++)
#pragma unroll
      for (int r = 0; r < 4; r++) acc[m][n][r] = 0.f;
  f32x4 pacc[MOE ? 4 : 1][MOE ? 4 : 1];
  if constexpr (MOE) {
#pragma unroll
    for (int m = 0; m < 4; m++)
#pragma unroll
      for (int n = 0; n < 4; n++)
#pragma unroll
        for (int r = 0; r < 4; r++) pacc[m][n][r] = 0.f;
  }

  const int srow = w * 8 + (lane >> 3);
  const int sdst = (lane & 7) * 8;
  const int ssrc = ((lane & 7) ^ ((lane >> 3) & 7)) * 8;
  const u16* Asrc = A + (long)(brow + srow) * KK + ssrc;
  const u16* Bsrc = WT + (long)(bcol + srow) * KK + ssrc;

  auto STAGE_H = [&](int t2, int buf, int h) {
    const int e2 = (E == 1) ? 0 : (t2 / KSTEPS);
    int k2 = (E == 1) ? t2 : (t2 % KSTEPS);
    if (E > 1 && (e2 & 1)) k2 = KSTEPS - 1 - k2;   // serpentine K
    const u16* ap = Asrc + (long)k2 * BK;
    const u16* bp = Bsrc + (long)e2 * ((long)N * KK) + (long)k2 * BK;
    GLDS(ap + (long)((h * 2 + 0) * 64) * KK, &As[buf][(h * 2 + 0) * 64 + srow][sdst]);
    GLDS(ap + (long)((h * 2 + 1) * 64) * KK, &As[buf][(h * 2 + 1) * 64 + srow][sdst]);
    GLDS(bp + (long)(h * 64) * KK,           &Bs[buf][h * 64 + srow][sdst]);
  };

  STAGE_H(0, 0, 0); STAGE_H(0, 0, 1);
  STAGE_H(1, 1, 0); STAGE_H(1, 1, 1);
  asm volatile("s_waitcnt vmcnt(6)" ::: "memory");
  asm volatile("s_barrier" ::: "memory");

  for (int t = 0; t < T; ++t) {
    const int cur = t % 3;
    const int nbuf = (t + 2) % 3;
    const bool do_stage = (t + 2 < T);

    { // phase 0 (kk=0)
      short8 af[4], bfr[4];
      const int cc = lk ^ xsw;
#pragma unroll
      for (int m = 0; m < 4; m++)
        af[m] = *(const short8*)&As[cur][wr * 64 + m * 16 + lr][cc];
#pragma unroll
      for (int n = 0; n < 4; n++)
        bfr[n] = *(const short8*)&Bs[cur][wc * 64 + n * 16 + lr][cc];
      if (do_stage) STAGE_H(t + 2, nbuf, 0);
      asm volatile("s_barrier" ::: "memory");
      __builtin_amdgcn_s_setprio(1);
#pragma unroll
      for (int m = 0; m < 4; m++)
#pragma unroll
        for (int n = 0; n < 4; n++) {
          if constexpr (MOE)
            pacc[m][n] = __builtin_amdgcn_mfma_f32_16x16x32_bf16(af[m], bfr[n], pacc[m][n], 0, 0, 0);
          else
            acc[m][n] = __builtin_amdgcn_mfma_f32_16x16x32_bf16(af[m], bfr[n], acc[m][n], 0, 0, 0);
        }
      __builtin_amdgcn_s_setprio(0);
      asm volatile("s_barrier" ::: "memory");
    }

    { // phase 1 (kk=32)
      short8 af[4], bfr[4];
      const int cc = (32 + lk) ^ xsw;
#pragma unroll
      for (int m = 0; m < 4; m++)
        af[m] = *(const short8*)&As[cur][wr * 64 + m * 16 + lr][cc];
#pragma unroll
      for (int n = 0; n < 4; n++)
        bfr[n] = *(const short8*)&Bs[cur][wc * 64 + n * 16 + lr][cc];
      if (do_stage) STAGE_H(t + 2, nbuf, 1);
      asm volatile("s_barrier" ::: "memory");
      __builtin_amdgcn_s_setprio(1);
#pragma unroll
      for (int m = 0; m < 4; m++)
#pragma unroll
        for (int n = 0; n < 4; n++) {
          if constexpr (MOE)
            pacc[m][n] = __builtin_amdgcn_mfma_f32_16x16x32_bf16(af[m], bfr[n], pacc[m][n], 0, 0, 0);
          else
            acc[m][n] = __builtin_amdgcn_mfma_f32_16x16x32_bf16(af[m], bfr[n], acc[m][n], 0, 0, 0);
        }
      __builtin_amdgcn_s_setprio(0);
      if (t + 1 < T) {
        if (do_stage) asm volatile("s_waitcnt vmcnt(6)" ::: "memory");
        else          asm volatile("s_waitcnt vmcnt(0)" ::: "memory");
      }
      asm volatile("s_barrier" ::: "memory");
    }

    if constexpr (MOE) {
      if ((t + 1) % KSTEPS == 0) {
        const int e = t / KSTEPS;
#pragma unroll
        for (int m = 0; m < 4; m++)
#pragma unroll
          for (int r = 0; r < 4; r++) {
            float c = Cf[wr * 64 + m * 16 + hi * 4 + r][e];
#pragma unroll
            for (int n = 0; n < 4; n++) acc[m][n][r] += c * pacc[m][n][r];
          }
        if (t + 1 < T) {
#pragma unroll
          for (int m = 0; m < 4; m++)
#pragma unroll
            for (int n = 0; n < 4; n++)
#pragma unroll
              for (int r = 0; r < 4; r++) pacc[m][n][r] = 0.f;
        }
      }
    }
  }

#pragma unroll
  for (int m = 0; m < 4; m++)
#pragma unroll
    for (int n = 0; n < 4; n++) {
      const int col = bcol + wc * 64 + n * 16 + lr;
#pragma unroll
      for (int r = 0; r < 4; r++) {
        const int rowl = wr * 64 + m * 16 + hi * 4 + r;
        const long row = brow + rowl;
        float v = acc[m][n][r];
        if constexpr (MOE) {
          float bv = 0.f;
#pragma unroll
          for (int e = 0; e < 6; e++) bv += Cf[rowl][e] * bias[(long)e * N + col];
          v += bv;
        } else {
          v += bias[col];
        }
        v = elu1(v);
        outH[row * (long)ldo + col] = f2b(v);
      }
    }
}

// ================= k_m2: 4-wave co-tenant GEMM (+MoE), BM=64, BN=128, BK=64.
// Same proven schedule as k_gemm8 (3-buffer ring, depth-2, counted vmcnt(6),
// fine 2-phase, setprio, 128B-row XOR swizzle). LDS 75.7KB -> 2 blocks/CU.
// Per-wave output 32x64 (waves 2x2). For mu/lv, gating, moe2.
template<int KSTEPS, int E, bool MOE>
__global__ __launch_bounds__(256, 2) void k_m2(
    const u16* __restrict__ A,
    const u16* __restrict__ WT,
    const float* __restrict__ bias, const float* __restrict__ bias2,
    const float* __restrict__ coeff,
    int N,
    u16* __restrict__ outH, float* __restrict__ outF, float* __restrict__ outF2,
    int ldo, int splitcol, int act)
{
  constexpr int KK = KSTEPS * BK;
  constexpr int T = E * KSTEPS;
  __shared__ __align__(16) u16 As[3][64][BK];
  __shared__ __align__(16) u16 Bs[3][128][BK];
  __shared__ float Cf[MOE ? 64 : 1][8];

  const int tid = threadIdx.x;
  const int lane = tid & 63, w = tid >> 6;       // 4 waves
  const int wr = w >> 1, wc = w & 1;             // 2 x 2; wave-tile 32x64
  const int brow = blockIdx.x * 64, bcol = blockIdx.y * 128;
  const int lr = lane & 15, hi = lane >> 4;
  const int lk = hi * 8;
  const int xsw = (lr & 7) << 3;

  if (MOE) {
    if (tid < 64) {
#pragma unroll
      for (int e2 = 0; e2 < 8; e2++)
        Cf[tid][e2] = (e2 < 6) ? coeff[(long)(brow + tid) * 6 + e2] : 0.f;
    }
    __syncthreads();
  }

  f32x4 acc[2][4];
#pragma unroll
  for (int m = 0; m < 2; m++)
#pragma unroll
    for (int n = 0; n < 4; n++)
#pragma unroll
      for (int r = 0; r < 4; r++) acc[m][n][r] = 0.f;
  f32x4 pacc[MOE ? 2 : 1][MOE ? 4 : 1];
  if constexpr (MOE) {
#pragma unroll
    for (int m = 0; m < 2; m++)
#pragma unroll
      for (int n = 0; n < 4; n++)
#pragma unroll
        for (int r = 0; r < 4; r++) pacc[m][n][r] = 0.f;
  }

  const int srow = w * 8 + (lane >> 3);          // 4 waves cover 32 rows/GLDS
  const int sdst = (lane & 7) * 8;
  const int ssrc = ((lane & 7) ^ ((lane >> 3) & 7)) * 8;
  const u16* Asrc = A + (long)(brow + srow) * KK + ssrc;
  const u16* Bsrc = WT + (long)(bcol + srow) * KK + ssrc;

  // half 0: A rows 0-31 + B rows 0-63 (3 GLDS); half 1: A 32-63 + B 64-127
  auto STAGE_H = [&](int t2, int buf, int h) {
    const int e2 = (E == 1) ? 0 : (t2 / KSTEPS);
    int k2 = (E == 1) ? t2 : (t2 % KSTEPS);
    if (E > 1 && (e2 & 1)) k2 = KSTEPS - 1 - k2;
    const u16* ap = Asrc + (long)k2 * BK;
    const u16* bp = Bsrc + (long)e2 * ((long)N * KK) + (long)k2 * BK;
    GLDS(ap + (long)(h * 32) * KK,            &As[buf][h * 32 + srow][sdst]);
    GLDS(bp + (long)(h * 64) * KK,            &Bs[buf][h * 64 + srow][sdst]);
    GLDS(bp + (long)(h * 64 + 32) * KK,       &Bs[buf][h * 64 + 32 + srow][sdst]);
  };

  STAGE_H(0, 0, 0); STAGE_H(0, 0, 1);
  STAGE_H(1, 1, 0); STAGE_H(1, 1, 1);
  asm volatile("s_waitcnt vmcnt(6)" ::: "memory");
  asm volatile("s_barrier" ::: "memory");

  for (int t = 0; t < T; ++t) {
    const int cur = t % 3;
    const int nbuf = (t + 2) % 3;
    const bool do_stage = (t + 2 < T);

    { // phase 0 (kk=0)
      short8 af[2], bfr[4];
      const int cc = lk ^ xsw;
#pragma unroll
      for (int m = 0; m < 2; m++)
        af[m] = *(const short8*)&As[cur][wr * 32 + m * 16 + lr][cc];
#pragma unroll
      for (int n = 0; n < 4; n++)
        bfr[n] = *(const short8*)&Bs[cur][wc * 64 + n * 16 + lr][cc];
      if (do_stage) STAGE_H(t + 2, nbuf, 0);
      asm volatile("s_barrier" ::: "memory");
      __builtin_amdgcn_s_setprio(1);
#pragma unroll
      for (int m = 0; m < 2; m++)
#pragma unroll
        for (int n = 0; n < 4; n++) {
          if constexpr (MOE)
            pacc[m][n] = __builtin_amdgcn_mfma_f32_16x16x32_bf16(af[m], bfr[n], pacc[m][n], 0, 0, 0);
          else
            acc[m][n] = __builtin_amdgcn_mfma_f32_16x16x32_bf16(af[m], bfr[n], acc[m][n], 0, 0, 0);
        }
      __builtin_amdgcn_s_setprio(0);
      asm volatile("s_barrier" ::: "memory");
    }

    { // phase 1 (kk=32)
      short8 af[2], bfr[4];
      const int cc = (32 + lk) ^ xsw;
#pragma unroll
      for (int m = 0; m < 2; m++)
        af[m] = *(const short8*)&As[cur][wr * 32 + m * 16 + lr][cc];
#pragma unroll
      for (int n = 0; n < 4; n++)
        bfr[n] = *(const short8*)&Bs[cur][wc * 64 + n * 16 + lr][cc];
      if (do_stage) STAGE_H(t + 2, nbuf, 1);
      asm volatile("s_barrier" ::: "memory");
      __builtin_amdgcn_s_setprio(1);
#pragma unroll
      for (int m = 0; m < 2; m++)
#pragma unroll
        for (int n = 0; n < 4; n++) {
          if constexpr (MOE)
            pacc[m][n] = __builtin_amdgcn_mfma_f32_16x16x32_bf16(af[m], bfr[n], pacc[m][n], 0, 0, 0);
          else
            acc[m][n] = __builtin_amdgcn_mfma_f32_16x16x32_bf16(af[m], bfr[n], acc[m][n], 0, 0, 0);
        }
      __builtin_amdgcn_s_setprio(0);
      if (t + 1 < T) {
        if (do_stage) asm volatile("s_waitcnt vmcnt(6)" ::: "memory");
        else          asm volatile("s_waitcnt vmcnt(0)" ::: "memory");
      }
      asm volatile("s_barrier" ::: "memory");
    }

    if constexpr (MOE) {
      if ((t + 1) % KSTEPS == 0) {
        const int e = t / KSTEPS;
#pragma unroll
        for (int m = 0; m < 2; m++)
#pragma unroll
          for (int r = 0; r < 4; r++) {
            float c = Cf[wr * 32 + m * 16 + hi * 4 + r][e];
#pragma unroll
            for (int n = 0; n < 4; n++) acc[m][n][r] += c * pacc[m][n][r];
          }
        if (t + 1 < T) {
#pragma unroll
          for (int m = 0; m < 2; m++)
#pragma unroll
            for (int n = 0; n < 4; n++)
#pragma unroll
              for (int r = 0; r < 4; r++) pacc[m][n][r] = 0.f;
        }
      }
    }
  }

#pragma unroll
  for (int m = 0; m < 2; m++)
#pragma unroll
    for (int n = 0; n < 4; n++) {
      const int col = bcol + wc * 64 + n * 16 + lr;
      if (col >= N) continue;
#pragma unroll
      for (int r = 0; r < 4; r++) {
        const int rowl = wr * 32 + m * 16 + hi * 4 + r;
        const long row = brow + rowl;
        float v = acc[m][n][r];
        if constexpr (MOE) {
          float bv = 0.f;
#pragma unroll
          for (int e = 0; e < 6; e++) bv += Cf[rowl][e] * bias[(long)e * N + col];
          v += bv;
        } else {
          v += (col < splitcol) ? bias[col] : bias2[col - splitcol];
        }
        if (act) v = elu1(v);
        if (outH) outH[row * (long)ldo + col] = f2b(v);
        else if (col < splitcol) outF[row * (long)ldo + col] = v;
        else outF2[row * (long)ldo + (col - splitcol)] = v;
      }
    }
}

extern "C" void kernel_launch(void* const* d_in, const int* in_sizes, int n_in,
                              void* d_out, int out_size, void* d_ws, size_t ws_size,
                              hipStream_t stream) {
  (void)in_sizes; (void)out_size;
  if (n_in < 23) return;
  const float* x      = (const float*)d_in[0];
  const float* y      = (const float*)d_in[1];
  const float* eps    = (const float*)d_in[2];
  const float* enc_w0 = (const float*)d_in[3];
  const float* enc_b0 = (const float*)d_in[4];
  const float* enc_w1 = (const float*)d_in[5];
  const float* enc_b1 = (const float*)d_in[6];
  const float* mu_w   = (const float*)d_in[7];
  const float* mu_b   = (const float*)d_in[8];
  const float* lv_w   = (const float*)d_in[9];
  const float* lv_b   = (const float*)d_in[10];
  const float* g_w0   = (const float*)d_in[11];
  const float* g_b0   = (const float*)d_in[12];
  const float* g_w1   = (const float*)d_in[13];
  const float* g_b1   = (const float*)d_in[14];
  const float* g_w2   = (const float*)d_in[15];
  const float* g_b2   = (const float*)d_in[16];
  const float* exp_w0 = (const float*)d_in[17];
  const float* exp_b0 = (const float*)d_in[18];
  const float* exp_w1 = (const float*)d_in[19];
  const float* exp_b1 = (const float*)d_in[20];
  const float* exp_w2 = (const float*)d_in[21];
  const float* exp_b2 = (const float*)d_in[22];

  char* ws = (char*)d_ws;
  size_t off = 0;
  auto alloc = [&](size_t bytes) -> void* {
    void* p = ws + off; off += (bytes + 255) & ~(size_t)255; return p;
  };
  u16* A0     = (u16*)alloc((size_t)B_ * K0_ * 2);        // enc0 input [x|y|x]; later D1
  u16* A1     = (u16*)alloc((size_t)B_ * K1_ * 2);        // enc1 input [h1|x]; later D2
  u16* H2     = (u16*)alloc((size_t)B_ * H_ * 2);         // enc2 output; later G1/COEFF/ew2T
  u16* ZY     = (u16*)alloc((size_t)B_ * INP_ * 2);       // [z|y]; later ew1T
  u16* encw0T = (u16*)alloc((size_t)K0_ * H_ * 2);
  u16* encw1T = (u16*)alloc((size_t)K1_ * H_ * 2);
  u16* mulvT  = (u16*)alloc((size_t)256 * H_ * 2);
  u16* gw0T   = (u16*)alloc((size_t)GH_ * INP_ * 2);      // OOB-read safe: ew0T follows
  u16* ew0T   = (u16*)alloc((size_t)NE_ * H_ * INP_ * 2);
  if (ws_size < off) return;

  // aliases (lifetime-checked):
  u16* D1 = A0;                                  // A0 dead after enc0
  u16* D2 = A1;                                  // A1 dead after enc1
  float* G1    = (float*)H2;                     // H2 dead after mu/lv
  float* COEFF = (float*)((char*)H2 + (size_t)B_ * GH_ * 4);
  u16* ew2T = (u16*)((char*)H2 + (size_t)4 * 1024 * 1024);   // transposed after mu/lv
  u16* ew1T = ZY;                                            // transposed after moe0

  float* outO = (float*)d_out;                       // [B,256]
  float* muO  = outO + (size_t)B_ * IN_;             // [B,128]
  float* lvO  = muO + (size_t)B_ * LAT_;             // [B,128]

  // 1. all upfront transposes + concat prep (one launch)
  k_pre<<<67400, 256, 0, stream>>>(enc_w0, enc_w1, mu_w, lv_w, g_w0, exp_w0,
      x, y, encw0T, encw1T, mulvT, gw0T, ew0T, A0, A1);

  // 2-3. encoder (8-wave fine-phase, 256x128 tiles, grid 256 blocks)
  k_gemm8<K0_ / BK, 1, false><<<dim3(32, 8), 512, 0, stream>>>(A0, encw0T, enc_b0,
      nullptr, H_, A1, K1_);
  k_gemm8<K1_ / BK, 1, false><<<dim3(32, 8), 512, 0, stream>>>(A1, encw1T, enc_b1,
      nullptr, H_, H2, H_);

  // 4. mu / logvar (k_m2 dense, split f32 into d_out)
  k_m2<H_ / BK, 1, false><<<dim3(B_ / 64, 2), 256, 0, stream>>>(H2, mulvT,
      mu_b, lv_b, nullptr, 256, nullptr, muO, lvO, LAT_, LAT_, 0);

  // 5. exp_w2 transpose + z/ZY/D1/D2 (one launch)
  k_mid<<<38592, 256, 0, stream>>>(exp_w2, ew2T, muO, lvO, eps, y, ZY, D1, D2);

  // 6. gating g1 (k_m2 dense, N=64; OOB B-rows read into ew0T region - safe)
  k_m2<INP_ / BK, 1, false><<<dim3(B_ / 64, 1), 256, 0, stream>>>(ZY, gw0T,
      g_b0, g_b0, nullptr, GH_, nullptr, G1, nullptr, GH_, GH_, 1);
  // 7. gating tail + softmax
  k_gate<<<B_ / 256, 256, 0, stream>>>(G1, g_w1, g_b1, g_w2, g_b2, COEFF);

  // 8. decoder MoE layer 0: ZY -> D1[:,128:1152]
  k_gemm8<INP_ / BK, NE_, true><<<dim3(32, 8), 512, 0, stream>>>(ZY, ew0T, exp_b0,
      COEFF, H_, D1 + LAT_, INP_);
  // 9. exp_w1 transpose into freed ZY space
  k_transpose<<<dim3(32, 36, NE_), dim3(32, 8), 0, stream>>>(exp_w1, ew1T, INP_, H_,
                                                    (long)INP_ * H_, (long)INP_ * H_);
  // 10. decoder MoE layer 1: D1 -> D2[:,128:1152]
  k_gemm8<INP_ / BK, NE_, true><<<dim3(32, 8), 512, 0, stream>>>(D1, ew1T, exp_b1,
      COEFF, H_, D2 + LAT_, INP_);
  // 11. decoder MoE layer 2: D2 -> d_out [B,256] f32 (k_m2 MoE)
  k_m2<INP_ / BK, NE_, true><<<dim3(B_ / 64, 2), 256, 0, stream>>>(D2, ew2T,
      exp_b2, nullptr, COEFF, IN_, nullptr, outO, nullptr, IN_, IN_, 0);
}